// Round 10
// baseline (291.729 us; speedup 1.0000x reference)
//
#include <hip/hip_runtime.h>

// FlyHash-style sparse projection + per-row exact top-k threshold.
//
// Round 10. R9's group-loop pipelining was eaten by a partial scratch spill
// (FETCH 108 MB / WRITE 232 MB): x4 stayed live across restage+barrier into
// loop-tail stores. Fix: reorder the tail so x4 dies AT the stores (R8's
// proven-clean live range), then restage, then a LGKM-ONLY barrier
// ("s_waitcnt lgkmcnt(0); s_barrier" asm — no vmcnt drain). Group g's
// 160 KB of nontemporal stores drain under group g+1's ~8us DS gather;
// the first full __syncthreads (phase1->2) lands after the gather.
// Next-group input loads are issued at the TOP of the iteration (vmcnt is
// in-order: the restage ds_write waits only for those older loads, not the
// younger stores). Register shape: x4[10]=40 + nf(4) + transients << 128.
// Bit-exactness (absmax 0, R2/R4-R9): serial f32 fold-left ascending ==
// ref einsum accumulation; threshold = an actual x value's bit pattern.

typedef float f4 __attribute__((ext_vector_type(4)));

constexpr int IN_F   = 512;
constexpr int OUT_F  = 10240;
constexpr int TPB    = 1024;
constexpr int ROWS   = 4;                 // batch rows per group
constexpr int GROUPS = 4;                 // row-groups per block
constexpr int FPT    = OUT_F / TPB;       // 10 features per thread
constexpr int NBINS  = 1024;              // per-row bins over [4,6), width 1/512
constexpr int CHUNK  = 8;
constexpr int NCHUNK = NBINS / CHUNK;     // 128 chunks per row
constexpr int NWAVES = TPB / 64;          // 16
constexpr int CAP    = 64;                // bracket-bin list capacity per row

// Workgroup barrier WITHOUT vmcnt drain: orders LDS (lgkm) only, so
// in-flight global stores keep draining across it.
__device__ __forceinline__ void barrier_lgkm() {
  __asm__ volatile("s_waitcnt lgkmcnt(0)\n\ts_barrier" ::: "memory");
}

// ---------------------------------------------------------------------------
// Kernel 1: extract sparse indices from dense W. One wave per W row.
// Emits indices ASCENDING (required for bit-exact fold-left downstream).
// ---------------------------------------------------------------------------
__global__ __launch_bounds__(256) void extract_idx(const float* __restrict__ W,
                                                   uint4* __restrict__ packed,
                                                   int out_f) {
  int row  = blockIdx.x * 4 + (threadIdx.x >> 6);
  int lane = threadIdx.x & 63;
  if (row >= out_f) return;

  const float* wr = W + (size_t)row * IN_F;
  unsigned long long masks[8];
#pragma unroll
  for (int c = 0; c < 8; ++c) {
    float v = wr[c * 64 + lane];
    masks[c] = __ballot(v != 0.0f);   // entries are exactly 0.0 or 1.0
  }
  if (lane == 0) {
    unsigned idx[6] = {IN_F, IN_F, IN_F, IN_F, IN_F, IN_F};  // pad -> zero slot
    int n = 0;
#pragma unroll
    for (int c = 0; c < 8; ++c) {
      unsigned long long m = masks[c];
      while (m && n < 6) {
        int b = __builtin_ctzll(m);
        idx[n++] = (unsigned)(c * 64 + b);
        m &= m - 1;
      }
    }
    uint4 r;
    r.x = idx[0] | (idx[1] << 16);
    r.y = idx[2] | (idx[3] << 16);
    r.z = idx[4] | (idx[5] << 16);
    r.w = (unsigned)n;
    packed[row] = r;
  }
}

// Serial fold of one row-component r (bit-identical to phase-1's fold).
__device__ __forceinline__ float row_val(const f4* in4, uint4 p, int r) {
  const float* b = (const float*)in4;
  float s = b[(p.x & 0xFFFFu) * 4 + r];
  s += b[(p.x >> 16) * 4 + r];
  s += b[(p.y & 0xFFFFu) * 4 + r];
  s += b[(p.y >> 16) * 4 + r];
  s += b[(p.z & 0xFFFFu) * 4 + r];
  s += b[(p.z >> 16) * 4 + r];
  return s;
}

// ---------------------------------------------------------------------------
// Kernel 2: 16 batch rows per block (4 groups of 4), 1024 threads.
// ---------------------------------------------------------------------------
__global__ __launch_bounds__(TPB, 4) void fly_hash(const float* __restrict__ inp,
                                                   const uint4* __restrict__ packed,
                                                   const int* __restrict__ kptr,
                                                   float* __restrict__ out) {
  __shared__ f4    in4[IN_F + 1];       // 8.2 KB; [IN_F] = zero slot for pads
  __shared__ int   hist[ROWS * NBINS];  // 16 KB
  __shared__ int   csum[ROWS * NCHUNK]; // 2 KB
  __shared__ int   wsum[NWAVES];
  __shared__ int   sh_bstar[ROWS], sh_above[ROWS], sh_n[ROWS], sh_cnt[ROWS];
  __shared__ float sh_list[ROWS][CAP];
  __shared__ float sh_thr[ROWS];
  __shared__ int   sh_need[ROWS];       // 1 -> fallback binary search

  const int tid  = threadIdx.x;
  const int lane = tid & 63;
  const int wid  = tid >> 6;
  const int k    = *kptr;               // hash_length (32)
  const int blockRow0 = blockIdx.x * (ROWS * GROUPS);

  // --- preamble: stage group 0's rows transposed into LDS + clean state --
  if (tid < IN_F) {
    const float* p = inp + (size_t)blockRow0 * IN_F + tid;
    f4 v;
    v.x = p[0];
    v.y = p[IN_F];
    v.z = p[2 * IN_F];
    v.w = p[3 * IN_F];
    in4[tid] = v;                       // ds_write_b128, conflict-free
  } else if (tid == IN_F) {
    f4 z = {0.0f, 0.0f, 0.0f, 0.0f};
    in4[IN_F] = z;
  }
  if (tid < ROWS) { sh_bstar[tid] = -1; sh_cnt[tid] = 0; }
  for (int i = tid; i < ROWS * NBINS; i += TPB) hist[i] = 0;
  __syncthreads();

#pragma unroll 1
  for (int g = 0; g < GROUPS; ++g) {
    const int row0 = blockRow0 + g * ROWS;
    const bool havenext = (g + 1 < GROUPS);

    // --- issue NEXT group's input loads early (oldest vmcnt entries) ----
    f4 nf = {0.0f, 0.0f, 0.0f, 0.0f};
    if (havenext && tid < IN_F) {
      const float* p = inp + (size_t)(row0 + ROWS) * IN_F + tid;
      nf.x = p[0];
      nf.y = p[IN_F];
      nf.z = p[2 * IN_F];
      nf.w = p[3 * IN_F];
    }

    // --- phase 1: compute x (bit-exact serial fold-left) + histogram -----
    f4 x4[FPT];
#pragma unroll
    for (int i = 0; i < FPT; ++i) {
      uint4 r = packed[tid + i * TPB];
      f4 s = in4[r.x & 0xFFFFu];        // ds_read_b128: 4 rows per gather
      s += in4[r.x >> 16];
      s += in4[r.y & 0xFFFFu];
      s += in4[r.y >> 16];
      s += in4[r.z & 0xFFFFu];
      s += in4[r.z >> 16];
      x4[i] = s;
#pragma unroll
      for (int rr = 0; rr < ROWS; ++rr) {
        float v = s[rr];
        if (v >= 4.0f) {                // top-32 of 10240 ~ 4.8; bin >=4 only
          int b = (int)((v - 4.0f) * 512.0f);  // EXACT key (Sterbenz + pow2)
          b = b > NBINS - 1 ? NBINS - 1 : b;
          atomicAdd(&hist[rr * NBINS + b], 1);
        }
      }
    }
    __syncthreads();   // full drain: prev group's stores are ~done by now

    // --- phase 2: per-row bracket bin via suffix scan (512 active) -------
    {
      const bool active = tid < ROWS * NCHUNK;   // 512
      const int r = tid >> 7;           // row (0..3) when active
      const int c = tid & (NCHUNK - 1); // chunk within row
      if (active) {
        const int base = r * NBINS + c * CHUNK;
        int ssum = 0;
#pragma unroll
        for (int j = 0; j < CHUNK; ++j) ssum += hist[base + j];
        csum[tid] = ssum;
      }
      __syncthreads();
      for (int st = 1; st < NCHUNK; st <<= 1) {
        int v = 0;
        if (active) v = csum[tid] + ((c + st < NCHUNK) ? csum[tid + st] : 0);
        __syncthreads();
        if (active) csum[tid] = v;
        __syncthreads();
      }
      if (active) {
        int above_chunk = (c + 1 < NCHUNK) ? csum[tid + 1] : 0;
        if (csum[tid] >= k && above_chunk < k) { // unique crossing chunk
          int acc = above_chunk;
          int bsel = c * CHUNK, abv = above_chunk;
          for (int b = c * CHUNK + CHUNK - 1; b >= c * CHUNK; --b) {
            int h = hist[r * NBINS + b];
            if (acc + h >= k) { bsel = b; abv = acc; break; }
            acc += h;
          }
          sh_bstar[r] = bsel;
          sh_above[r] = abv;
          sh_n[r]     = hist[r * NBINS + bsel];
        }
      }
    }
    __syncthreads();

    // --- phase 3a: collect bracket-bin members into per-row lists --------
    {
      const int b0 = sh_bstar[0], b1 = sh_bstar[1];
      const int b2 = sh_bstar[2], b3 = sh_bstar[3];
#pragma unroll
      for (int i = 0; i < FPT; ++i) {
        f4 s = x4[i];
#pragma unroll
        for (int rr = 0; rr < ROWS; ++rr) {
          float v = s[rr];
          int bb = (rr == 0) ? b0 : (rr == 1) ? b1 : (rr == 2) ? b2 : b3;
          if (v >= 4.0f) {
            int b = (int)((v - 4.0f) * 512.0f);
            b = b > NBINS - 1 ? NBINS - 1 : b;
            if (b == bb) {
              int p = atomicAdd(&sh_cnt[rr], 1);
              if (p < CAP) sh_list[rr][p] = v;
            }
          }
        }
      }
    }
    __syncthreads();

    // --- phase 3b: wave r rank-selects the (k-above)-th largest ----------
    if (wid < ROWS) {
      const int r   = wid;
      const int bst = sh_bstar[r];
      const int n   = (bst >= 0) ? sh_n[r] : CAP + 1;
      if (bst >= 0 && n <= CAP && sh_cnt[r] <= CAP) {
        const int j = k - sh_above[r];          // 1 <= j <= n
        float vl = (lane < n) ? sh_list[r][lane] : -1.0f;
        int cgt = 0, cge = 0;
        for (int m = 0; m < n; ++m) {
          float u = sh_list[r][m];              // broadcast LDS read
          cgt += (u > vl);
          cge += (u >= vl);
        }
        if (lane < n && cgt < j && cge >= j) sh_thr[r] = vl;  // exact bits
        if (lane == 0) sh_need[r] = 0;
      } else {
        if (lane == 0) sh_need[r] = 1;          // overflow / no bracket
      }
    }
    __syncthreads();

    // --- phase 4: fallback (recomputes from LDS; block-uniform; rare) ----
#pragma unroll 1
    for (int r = 0; r < ROWS; ++r) {
      if (!sh_need[r]) continue;
      unsigned lo = 0u, hi = __float_as_uint(8.0f);
      while (lo < hi) {
        unsigned mid = lo + ((hi - lo + 1u) >> 1);
        float fm = __uint_as_float(mid);
        int c = 0;
        for (int i = 0; i < FPT; ++i) {
          uint4 p = packed[tid + i * TPB];
          c += (int)__popcll(__ballot(row_val(in4, p, r) >= fm));
        }
        if (lane == 0) wsum[wid] = c;
        __syncthreads();
        int tot = 0;
#pragma unroll
        for (int w = 0; w < NWAVES; ++w) tot += wsum[w];
        if (tot >= k) lo = mid; else hi = mid - 1u;
        __syncthreads();
      }
      if (tid == 0) sh_thr[r] = __uint_as_float(lo);
      __syncthreads();
    }
    const float t0 = sh_thr[0];
    const float t1 = sh_thr[1];
    const float t2 = sh_thr[2];
    const float t3 = sh_thr[3];

    // --- stores for group g: x4's live range ENDS here -------------------
    {
      float* o0 = out + (size_t)(row0 + 0) * OUT_F;
      float* o1 = out + (size_t)(row0 + 1) * OUT_F;
      float* o2 = out + (size_t)(row0 + 2) * OUT_F;
      float* o3 = out + (size_t)(row0 + 3) * OUT_F;
#pragma unroll
      for (int i = 0; i < FPT; ++i) {
        int f = tid + i * TPB;
        f4 v = x4[i];
        __builtin_nontemporal_store((v.x >= t0) ? v.x : 0.0f, &o0[f]);
        __builtin_nontemporal_store((v.y >= t1) ? v.y : 0.0f, &o1[f]);
        __builtin_nontemporal_store((v.z >= t2) ? v.z : 0.0f, &o2[f]);
        __builtin_nontemporal_store((v.w >= t3) ? v.w : 0.0f, &o3[f]);
      }
    }

    // --- restage for group g+1 (ds_write waits only on the OLDER nf loads,
    // not the younger stores: vmcnt is in-order) -------------------------
    if (havenext) {
      if (tid < IN_F) {
        in4[tid] = nf;
      } else if (tid == IN_F) {
        f4 z = {0.0f, 0.0f, 0.0f, 0.0f};
        in4[IN_F] = z;
      }
      if (tid < ROWS) { sh_bstar[tid] = -1; sh_cnt[tid] = 0; }
      for (int i = tid; i < ROWS * NBINS; i += TPB) hist[i] = 0;
    }

    // --- LGKM-only barrier: stores keep draining into next group's gather
    barrier_lgkm();
  }
}

// ---------------------------------------------------------------------------
extern "C" void kernel_launch(void* const* d_in, const int* in_sizes, int n_in,
                              void* d_out, int out_size, void* d_ws, size_t ws_size,
                              hipStream_t stream) {
  const float* inp = (const float*)d_in[0];
  const float* W   = (const float*)d_in[1];
  const int* kptr  = (const int*)d_in[2];
  float* out       = (float*)d_out;

  const int batch = in_sizes[0] / IN_F;   // 4096
  const int out_f = in_sizes[1] / IN_F;   // 10240

  uint4* packed = (uint4*)d_ws;           // 10240 * 16 B = 160 KB scratch

  hipLaunchKernelGGL(extract_idx, dim3((out_f + 3) / 4), dim3(256), 0, stream,
                     W, packed, out_f);
  hipLaunchKernelGGL(fly_hash, dim3(batch / (ROWS * GROUPS)), dim3(TPB), 0,
                     stream, inp, packed, kptr, out);
}

// Round 11
// 250.951 us; speedup vs baseline: 1.1625x; 1.1625x over previous
//
#include <hip/hip_runtime.h>

// FlyHash-style sparse projection + per-row exact top-k threshold.
//
// Round 11 = R8's code with __launch_bounds__(1024, 8).
// R8 (best, fly ~80us inferred, clean FETCH/WRITE) ran 1 block/CU: its
// store phase (160 KB) and LDS-gather phase serialize per CU. All loop-based
// pipelining attempts (R6/R9/R10) died to register-allocator spills. This
// round gets the overlap WITHOUT new live state: the 64-VGPR cap admits 2
// co-resident 1024-thread blocks/CU (LDS 2x28KB, 32 waves), so one block's
// store drain runs under the other block's DS gather. Why this should fit
// where R5 didn't: R5's fallback referenced x4 (kept 40 regs live across the
// whole search + lo/hi/mid state); R8/R11's fallback recomputes from LDS and
// never touches x4 -> high-water = phase1's 40 persisted + ~20 transient.
// If FETCH/WRITE inflate again (spill), revert to R8 verbatim.
// Bit-exactness (absmax 0, R2/R4-R10): serial f32 fold-left ascending ==
// ref einsum accumulation; threshold = an actual x value's bit pattern.

typedef float f4 __attribute__((ext_vector_type(4)));

constexpr int IN_F   = 512;
constexpr int OUT_F  = 10240;
constexpr int TPB    = 1024;
constexpr int ROWS   = 4;                 // batch rows per block
constexpr int FPT    = OUT_F / TPB;       // 10 features per thread
constexpr int NBINS  = 1024;              // per-row bins over [4,6), width 1/512
constexpr int CHUNK  = 8;
constexpr int NCHUNK = NBINS / CHUNK;     // 128 chunks per row
constexpr int NWAVES = TPB / 64;          // 16
constexpr int CAP    = 64;                // bracket-bin list capacity per row

// ---------------------------------------------------------------------------
// Kernel 1: extract sparse indices from dense W. One wave per W row.
// Emits indices ASCENDING (required for bit-exact fold-left downstream).
// ---------------------------------------------------------------------------
__global__ __launch_bounds__(256) void extract_idx(const float* __restrict__ W,
                                                   uint4* __restrict__ packed,
                                                   int out_f) {
  int row  = blockIdx.x * 4 + (threadIdx.x >> 6);
  int lane = threadIdx.x & 63;
  if (row >= out_f) return;

  const float* wr = W + (size_t)row * IN_F;
  unsigned long long masks[8];
#pragma unroll
  for (int c = 0; c < 8; ++c) {
    float v = wr[c * 64 + lane];
    masks[c] = __ballot(v != 0.0f);   // entries are exactly 0.0 or 1.0
  }
  if (lane == 0) {
    unsigned idx[6] = {IN_F, IN_F, IN_F, IN_F, IN_F, IN_F};  // pad -> zero slot
    int n = 0;
#pragma unroll
    for (int c = 0; c < 8; ++c) {
      unsigned long long m = masks[c];
      while (m && n < 6) {
        int b = __builtin_ctzll(m);
        idx[n++] = (unsigned)(c * 64 + b);
        m &= m - 1;
      }
    }
    uint4 r;
    r.x = idx[0] | (idx[1] << 16);
    r.y = idx[2] | (idx[3] << 16);
    r.z = idx[4] | (idx[5] << 16);
    r.w = (unsigned)n;
    packed[row] = r;
  }
}

// Serial fold of one row-component r (bit-identical to phase-1's fold).
__device__ __forceinline__ float row_val(const f4* in4, uint4 p, int r) {
  const float* b = (const float*)in4;
  float s = b[(p.x & 0xFFFFu) * 4 + r];
  s += b[(p.x >> 16) * 4 + r];
  s += b[(p.y & 0xFFFFu) * 4 + r];
  s += b[(p.y >> 16) * 4 + r];
  s += b[(p.z & 0xFFFFu) * 4 + r];
  s += b[(p.z >> 16) * 4 + r];
  return s;
}

// ---------------------------------------------------------------------------
// Kernel 2: 4 batch rows per block, 1024 threads, x4[10] persisted (40 VGPR).
// __launch_bounds__(1024,8): 64-VGPR cap -> 2 blocks/CU co-resident.
// ---------------------------------------------------------------------------
__global__ __launch_bounds__(TPB, 8) void fly_hash(const float* __restrict__ inp,
                                                   const uint4* __restrict__ packed,
                                                   const int* __restrict__ kptr,
                                                   float* __restrict__ out) {
  __shared__ f4    in4[IN_F + 1];       // 8.2 KB; [IN_F] = zero slot for pads
  __shared__ int   hist[ROWS * NBINS];  // 16 KB
  __shared__ int   csum[ROWS * NCHUNK]; // 2 KB
  __shared__ int   wsum[NWAVES];
  __shared__ int   sh_bstar[ROWS], sh_above[ROWS], sh_n[ROWS], sh_cnt[ROWS];
  __shared__ float sh_list[ROWS][CAP];
  __shared__ float sh_thr[ROWS];
  __shared__ int   sh_need[ROWS];       // 1 -> fallback binary search

  const int tid  = threadIdx.x;
  const int lane = tid & 63;
  const int wid  = tid >> 6;
  const int row0 = blockIdx.x * ROWS;
  const int k    = *kptr;               // hash_length (32)

  // --- stage 4 input rows transposed into LDS ---------------------------
  if (tid < IN_F) {
    const float* p = inp + (size_t)row0 * IN_F + tid;
    f4 v;
    v.x = p[0];
    v.y = p[IN_F];
    v.z = p[2 * IN_F];
    v.w = p[3 * IN_F];
    in4[tid] = v;                       // ds_write_b128, conflict-free
  } else if (tid == IN_F) {
    f4 z = {0.0f, 0.0f, 0.0f, 0.0f};
    in4[IN_F] = z;
  }
  if (tid < ROWS) { sh_bstar[tid] = -1; sh_cnt[tid] = 0; }
  for (int i = tid; i < ROWS * NBINS; i += TPB) hist[i] = 0;
  __syncthreads();

  // --- phase 1: compute x (bit-exact serial fold-left) + histogram -------
  f4 x4[FPT];
#pragma unroll
  for (int i = 0; i < FPT; ++i) {
    uint4 r = packed[tid + i * TPB];
    f4 s = in4[r.x & 0xFFFFu];          // ds_read_b128: 4 rows per gather
    s += in4[r.x >> 16];
    s += in4[r.y & 0xFFFFu];
    s += in4[r.y >> 16];
    s += in4[r.z & 0xFFFFu];
    s += in4[r.z >> 16];
    x4[i] = s;
#pragma unroll
    for (int rr = 0; rr < ROWS; ++rr) {
      float v = s[rr];
      if (v >= 4.0f) {                  // top-32 of 10240 ~ 4.8; bin >=4 only
        int b = (int)((v - 4.0f) * 512.0f);    // EXACT key (Sterbenz + pow2)
        b = b > NBINS - 1 ? NBINS - 1 : b;
        atomicAdd(&hist[rr * NBINS + b], 1);
      }
    }
  }
  __syncthreads();

  // --- phase 2: per-row bracket bin via suffix scan (512 of 1024 active) --
  {
    const bool active = tid < ROWS * NCHUNK;   // 512
    const int r = tid >> 7;             // row (0..3) when active
    const int c = tid & (NCHUNK - 1);   // chunk within row
    if (active) {
      const int base = r * NBINS + c * CHUNK;
      int ssum = 0;
#pragma unroll
      for (int j = 0; j < CHUNK; ++j) ssum += hist[base + j];
      csum[tid] = ssum;
    }
    __syncthreads();
    for (int st = 1; st < NCHUNK; st <<= 1) {
      int v = 0;
      if (active) v = csum[tid] + ((c + st < NCHUNK) ? csum[tid + st] : 0);
      __syncthreads();
      if (active) csum[tid] = v;
      __syncthreads();
    }
    if (active) {
      int above_chunk = (c + 1 < NCHUNK) ? csum[tid + 1] : 0;
      if (csum[tid] >= k && above_chunk < k) {   // unique crossing chunk
        int acc = above_chunk;
        int bsel = c * CHUNK, abv = above_chunk;
        for (int b = c * CHUNK + CHUNK - 1; b >= c * CHUNK; --b) {
          int h = hist[r * NBINS + b];
          if (acc + h >= k) { bsel = b; abv = acc; break; }
          acc += h;
        }
        sh_bstar[r] = bsel;
        sh_above[r] = abv;
        sh_n[r]     = hist[r * NBINS + bsel];
      }
    }
  }
  __syncthreads();

  // --- phase 3a: collect bracket-bin members into per-row lists ----------
  {
    const int b0 = sh_bstar[0], b1 = sh_bstar[1];
    const int b2 = sh_bstar[2], b3 = sh_bstar[3];
#pragma unroll
    for (int i = 0; i < FPT; ++i) {
      f4 s = x4[i];
#pragma unroll
      for (int rr = 0; rr < ROWS; ++rr) {
        float v = s[rr];
        int bb = (rr == 0) ? b0 : (rr == 1) ? b1 : (rr == 2) ? b2 : b3;
        if (v >= 4.0f) {
          int b = (int)((v - 4.0f) * 512.0f);
          b = b > NBINS - 1 ? NBINS - 1 : b;
          if (b == bb) {
            int p = atomicAdd(&sh_cnt[rr], 1);
            if (p < CAP) sh_list[rr][p] = v;
          }
        }
      }
    }
  }
  __syncthreads();

  // --- phase 3b: wave r rank-selects the (k-above)-th largest in its list -
  if (wid < ROWS) {
    const int r   = wid;
    const int bst = sh_bstar[r];
    const int n   = (bst >= 0) ? sh_n[r] : CAP + 1;
    if (bst >= 0 && n <= CAP && sh_cnt[r] <= CAP) {
      const int j = k - sh_above[r];            // 1 <= j <= n
      float vl = (lane < n) ? sh_list[r][lane] : -1.0f;
      int cgt = 0, cge = 0;
      for (int m = 0; m < n; ++m) {
        float u = sh_list[r][m];                // broadcast LDS read
        cgt += (u > vl);
        cge += (u >= vl);
      }
      if (lane < n && cgt < j && cge >= j) sh_thr[r] = vl;  // exact k-th bits
      if (lane == 0) sh_need[r] = 0;
    } else {
      if (lane == 0) sh_need[r] = 1;            // overflow / no bracket
    }
  }
  __syncthreads();

  // --- phase 4: fallback (recomputes from LDS, never touches x4; rare) ---
#pragma unroll 1
  for (int r = 0; r < ROWS; ++r) {
    if (!sh_need[r]) continue;
    unsigned lo = 0u, hi = __float_as_uint(8.0f);
    while (lo < hi) {
      unsigned mid = lo + ((hi - lo + 1u) >> 1);
      float fm = __uint_as_float(mid);
      int c = 0;
      for (int i = 0; i < FPT; ++i) {
        uint4 p = packed[tid + i * TPB];
        c += (int)__popcll(__ballot(row_val(in4, p, r) >= fm));
      }
      if (lane == 0) wsum[wid] = c;
      __syncthreads();
      int tot = 0;
#pragma unroll
      for (int w = 0; w < NWAVES; ++w) tot += wsum[w];
      if (tot >= k) lo = mid; else hi = mid - 1u;
      __syncthreads();
    }
    if (tid == 0) sh_thr[r] = __uint_as_float(lo);
    __syncthreads();
  }
  const float t0 = sh_thr[0];
  const float t1 = sh_thr[1];
  const float t2 = sh_thr[2];
  const float t3 = sh_thr[3];

  // --- phase 5: thresholded writes, 4 coalesced nontemporal streams ------
  float* o0 = out + (size_t)(row0 + 0) * OUT_F;
  float* o1 = out + (size_t)(row0 + 1) * OUT_F;
  float* o2 = out + (size_t)(row0 + 2) * OUT_F;
  float* o3 = out + (size_t)(row0 + 3) * OUT_F;
#pragma unroll
  for (int i = 0; i < FPT; ++i) {
    int f = tid + i * TPB;
    f4 v = x4[i];
    __builtin_nontemporal_store((v.x >= t0) ? v.x : 0.0f, &o0[f]);
    __builtin_nontemporal_store((v.y >= t1) ? v.y : 0.0f, &o1[f]);
    __builtin_nontemporal_store((v.z >= t2) ? v.z : 0.0f, &o2[f]);
    __builtin_nontemporal_store((v.w >= t3) ? v.w : 0.0f, &o3[f]);
  }
}

// ---------------------------------------------------------------------------
extern "C" void kernel_launch(void* const* d_in, const int* in_sizes, int n_in,
                              void* d_out, int out_size, void* d_ws, size_t ws_size,
                              hipStream_t stream) {
  const float* inp = (const float*)d_in[0];
  const float* W   = (const float*)d_in[1];
  const int* kptr  = (const int*)d_in[2];
  float* out       = (float*)d_out;

  const int batch = in_sizes[0] / IN_F;   // 4096
  const int out_f = in_sizes[1] / IN_F;   // 10240

  uint4* packed = (uint4*)d_ws;           // 10240 * 16 B = 160 KB scratch

  hipLaunchKernelGGL(extract_idx, dim3((out_f + 3) / 4), dim3(256), 0, stream,
                     W, packed, out_f);
  hipLaunchKernelGGL(fly_hash, dim3(batch / ROWS), dim3(TPB), 0, stream,
                     inp, packed, kptr, out);
}

// Round 12
// 237.431 us; speedup vs baseline: 1.2287x; 1.0569x over previous
//
#include <hip/hip_runtime.h>

// FlyHash-style sparse projection + per-row exact top-k threshold.
//
// Round 12 = R8 (champion, ~78us inferred, clean traffic) with phase 2's
// 16-barrier Hillis-Steele scan replaced by a wave-parallel register scan:
// wave r (r<ROWS) owns row r; lane L serially sums bins [16L,16L+16),
// 6-step __shfl_down suffix scan, the crossing lane walks its 16 bins to
// the exact bracket bin. 2 barriers instead of ~16, csum[] eliminated.
// All else identical to R8: ds_read_b128 gathers (ROWS=4), zero-iteration
// list-select, LDS-recompute fallback, nontemporal stores,
// __launch_bounds__(1024,4) (the proven spill-free register shape; R11's
// (1024,8) cap and all loop pipelining variants R6/R9/R10 regressed).
// Bit-exactness (absmax 0, R2/R4-R11): serial f32 fold-left ascending ==
// ref einsum accumulation; threshold = an actual x value's bit pattern.

typedef float f4 __attribute__((ext_vector_type(4)));

constexpr int IN_F   = 512;
constexpr int OUT_F  = 10240;
constexpr int TPB    = 1024;
constexpr int ROWS   = 4;                 // batch rows per block
constexpr int FPT    = OUT_F / TPB;       // 10 features per thread
constexpr int NBINS  = 1024;              // per-row bins over [4,6), width 1/512
constexpr int NWAVES = TPB / 64;          // 16
constexpr int CAP    = 64;                // bracket-bin list capacity per row

static_assert(NBINS == 64 * 16, "wave scan assumes 16 bins per lane");

// ---------------------------------------------------------------------------
// Kernel 1: extract sparse indices from dense W. One wave per W row.
// Emits indices ASCENDING (required for bit-exact fold-left downstream).
// ---------------------------------------------------------------------------
__global__ __launch_bounds__(256) void extract_idx(const float* __restrict__ W,
                                                   uint4* __restrict__ packed,
                                                   int out_f) {
  int row  = blockIdx.x * 4 + (threadIdx.x >> 6);
  int lane = threadIdx.x & 63;
  if (row >= out_f) return;

  const float* wr = W + (size_t)row * IN_F;
  unsigned long long masks[8];
#pragma unroll
  for (int c = 0; c < 8; ++c) {
    float v = wr[c * 64 + lane];
    masks[c] = __ballot(v != 0.0f);   // entries are exactly 0.0 or 1.0
  }
  if (lane == 0) {
    unsigned idx[6] = {IN_F, IN_F, IN_F, IN_F, IN_F, IN_F};  // pad -> zero slot
    int n = 0;
#pragma unroll
    for (int c = 0; c < 8; ++c) {
      unsigned long long m = masks[c];
      while (m && n < 6) {
        int b = __builtin_ctzll(m);
        idx[n++] = (unsigned)(c * 64 + b);
        m &= m - 1;
      }
    }
    uint4 r;
    r.x = idx[0] | (idx[1] << 16);
    r.y = idx[2] | (idx[3] << 16);
    r.z = idx[4] | (idx[5] << 16);
    r.w = (unsigned)n;
    packed[row] = r;
  }
}

// Serial fold of one row-component r (bit-identical to phase-1's fold).
__device__ __forceinline__ float row_val(const f4* in4, uint4 p, int r) {
  const float* b = (const float*)in4;
  float s = b[(p.x & 0xFFFFu) * 4 + r];
  s += b[(p.x >> 16) * 4 + r];
  s += b[(p.y & 0xFFFFu) * 4 + r];
  s += b[(p.y >> 16) * 4 + r];
  s += b[(p.z & 0xFFFFu) * 4 + r];
  s += b[(p.z >> 16) * 4 + r];
  return s;
}

// ---------------------------------------------------------------------------
// Kernel 2: 4 batch rows per block, 1024 threads, x4[10] persisted (40 VGPR).
// ---------------------------------------------------------------------------
__global__ __launch_bounds__(TPB, 4) void fly_hash(const float* __restrict__ inp,
                                                   const uint4* __restrict__ packed,
                                                   const int* __restrict__ kptr,
                                                   float* __restrict__ out) {
  __shared__ f4    in4[IN_F + 1];       // 8.2 KB; [IN_F] = zero slot for pads
  __shared__ int   hist[ROWS * NBINS];  // 16 KB
  __shared__ int   wsum[NWAVES];
  __shared__ int   sh_bstar[ROWS], sh_above[ROWS], sh_n[ROWS], sh_cnt[ROWS];
  __shared__ float sh_list[ROWS][CAP];
  __shared__ float sh_thr[ROWS];
  __shared__ int   sh_need[ROWS];       // 1 -> fallback binary search

  const int tid  = threadIdx.x;
  const int lane = tid & 63;
  const int wid  = tid >> 6;
  const int row0 = blockIdx.x * ROWS;
  const int k    = *kptr;               // hash_length (32)

  // --- stage 4 input rows transposed into LDS ---------------------------
  if (tid < IN_F) {
    const float* p = inp + (size_t)row0 * IN_F + tid;
    f4 v;
    v.x = p[0];
    v.y = p[IN_F];
    v.z = p[2 * IN_F];
    v.w = p[3 * IN_F];
    in4[tid] = v;                       // ds_write_b128, conflict-free
  } else if (tid == IN_F) {
    f4 z = {0.0f, 0.0f, 0.0f, 0.0f};
    in4[IN_F] = z;
  }
  if (tid < ROWS) { sh_bstar[tid] = -1; sh_cnt[tid] = 0; }
  for (int i = tid; i < ROWS * NBINS; i += TPB) hist[i] = 0;
  __syncthreads();

  // --- phase 1: compute x (bit-exact serial fold-left) + histogram -------
  f4 x4[FPT];
#pragma unroll
  for (int i = 0; i < FPT; ++i) {
    uint4 r = packed[tid + i * TPB];
    f4 s = in4[r.x & 0xFFFFu];          // ds_read_b128: 4 rows per gather
    s += in4[r.x >> 16];
    s += in4[r.y & 0xFFFFu];
    s += in4[r.y >> 16];
    s += in4[r.z & 0xFFFFu];
    s += in4[r.z >> 16];
    x4[i] = s;
#pragma unroll
    for (int rr = 0; rr < ROWS; ++rr) {
      float v = s[rr];
      if (v >= 4.0f) {                  // top-32 of 10240 ~ 4.8; bin >=4 only
        int b = (int)((v - 4.0f) * 512.0f);    // EXACT key (Sterbenz + pow2)
        b = b > NBINS - 1 ? NBINS - 1 : b;
        atomicAdd(&hist[rr * NBINS + b], 1);
      }
    }
  }
  __syncthreads();

  // --- phase 2: wave-parallel bracket-bin search (wave r owns row r) -----
  // Lane L sums bins [16L, 16L+16); 6-step shfl suffix scan; crossing lane
  // walks its 16 bins descending to the exact bin. No internal barriers.
  if (wid < ROWS) {
    const int r = wid;
    const int base = r * NBINS + lane * 16;
    int csum = 0;
#pragma unroll
    for (int j = 0; j < 16; ++j) csum += hist[base + j];
    int s = csum;                       // inclusive suffix sum across lanes
#pragma unroll
    for (int off = 1; off < 64; off <<= 1) {
      int t = __shfl_down(s, off);
      if (lane + off < 64) s += t;
    }
    int s_next = __shfl_down(s, 1);     // suffix starting at lane+1
    if (lane == 63) s_next = 0;
    if (s >= k && s_next < k) {         // unique crossing chunk (if any)
      int acc = s_next;
      int bsel = lane * 16, abv = s_next;
      for (int b = lane * 16 + 15; b >= lane * 16; --b) {
        int h = hist[r * NBINS + b];
        if (acc + h >= k) { bsel = b; abv = acc; break; }
        acc += h;
      }
      sh_bstar[r] = bsel;
      sh_above[r] = abv;
      sh_n[r]     = hist[r * NBINS + bsel];
    }
  }
  __syncthreads();

  // --- phase 3a: collect bracket-bin members into per-row lists ----------
  {
    const int b0 = sh_bstar[0], b1 = sh_bstar[1];
    const int b2 = sh_bstar[2], b3 = sh_bstar[3];
#pragma unroll
    for (int i = 0; i < FPT; ++i) {
      f4 s = x4[i];
#pragma unroll
      for (int rr = 0; rr < ROWS; ++rr) {
        float v = s[rr];
        int bb = (rr == 0) ? b0 : (rr == 1) ? b1 : (rr == 2) ? b2 : b3;
        if (v >= 4.0f) {
          int b = (int)((v - 4.0f) * 512.0f);
          b = b > NBINS - 1 ? NBINS - 1 : b;
          if (b == bb) {
            int p = atomicAdd(&sh_cnt[rr], 1);
            if (p < CAP) sh_list[rr][p] = v;
          }
        }
      }
    }
  }
  __syncthreads();

  // --- phase 3b: wave r rank-selects the (k-above)-th largest in its list -
  if (wid < ROWS) {
    const int r   = wid;
    const int bst = sh_bstar[r];
    const int n   = (bst >= 0) ? sh_n[r] : CAP + 1;
    if (bst >= 0 && n <= CAP && sh_cnt[r] <= CAP) {
      const int j = k - sh_above[r];            // 1 <= j <= n
      float vl = (lane < n) ? sh_list[r][lane] : -1.0f;
      int cgt = 0, cge = 0;
      for (int m = 0; m < n; ++m) {
        float u = sh_list[r][m];                // broadcast LDS read
        cgt += (u > vl);
        cge += (u >= vl);
      }
      if (lane < n && cgt < j && cge >= j) sh_thr[r] = vl;  // exact k-th bits
      if (lane == 0) sh_need[r] = 0;
    } else {
      if (lane == 0) sh_need[r] = 1;            // overflow / no bracket
    }
  }
  __syncthreads();

  // --- phase 4: fallback (recomputes from LDS, never touches x4; rare) ---
#pragma unroll 1
  for (int r = 0; r < ROWS; ++r) {
    if (!sh_need[r]) continue;
    unsigned lo = 0u, hi = __float_as_uint(8.0f);
    while (lo < hi) {
      unsigned mid = lo + ((hi - lo + 1u) >> 1);
      float fm = __uint_as_float(mid);
      int c = 0;
      for (int i = 0; i < FPT; ++i) {
        uint4 p = packed[tid + i * TPB];
        c += (int)__popcll(__ballot(row_val(in4, p, r) >= fm));
      }
      if (lane == 0) wsum[wid] = c;
      __syncthreads();
      int tot = 0;
#pragma unroll
      for (int w = 0; w < NWAVES; ++w) tot += wsum[w];
      if (tot >= k) lo = mid; else hi = mid - 1u;
      __syncthreads();
    }
    if (tid == 0) sh_thr[r] = __uint_as_float(lo);
    __syncthreads();
  }
  const float t0 = sh_thr[0];
  const float t1 = sh_thr[1];
  const float t2 = sh_thr[2];
  const float t3 = sh_thr[3];

  // --- phase 5: thresholded writes, 4 coalesced nontemporal streams ------
  float* o0 = out + (size_t)(row0 + 0) * OUT_F;
  float* o1 = out + (size_t)(row0 + 1) * OUT_F;
  float* o2 = out + (size_t)(row0 + 2) * OUT_F;
  float* o3 = out + (size_t)(row0 + 3) * OUT_F;
#pragma unroll
  for (int i = 0; i < FPT; ++i) {
    int f = tid + i * TPB;
    f4 v = x4[i];
    __builtin_nontemporal_store((v.x >= t0) ? v.x : 0.0f, &o0[f]);
    __builtin_nontemporal_store((v.y >= t1) ? v.y : 0.0f, &o1[f]);
    __builtin_nontemporal_store((v.z >= t2) ? v.z : 0.0f, &o2[f]);
    __builtin_nontemporal_store((v.w >= t3) ? v.w : 0.0f, &o3[f]);
  }
}

// ---------------------------------------------------------------------------
extern "C" void kernel_launch(void* const* d_in, const int* in_sizes, int n_in,
                              void* d_out, int out_size, void* d_ws, size_t ws_size,
                              hipStream_t stream) {
  const float* inp = (const float*)d_in[0];
  const float* W   = (const float*)d_in[1];
  const int* kptr  = (const int*)d_in[2];
  float* out       = (float*)d_out;

  const int batch = in_sizes[0] / IN_F;   // 4096
  const int out_f = in_sizes[1] / IN_F;   // 10240

  uint4* packed = (uint4*)d_ws;           // 10240 * 16 B = 160 KB scratch

  hipLaunchKernelGGL(extract_idx, dim3((out_f + 3) / 4), dim3(256), 0, stream,
                     W, packed, out_f);
  hipLaunchKernelGGL(fly_hash, dim3(batch / ROWS), dim3(TPB), 0, stream,
                     inp, packed, kptr, out);
}